// Round 1
// baseline (996.501 us; speedup 1.0000x reference)
//
#include <hip/hip_runtime.h>
#include <hip/hip_bf16.h>
#include <hip/hip_fp16.h>
#include <stdint.h>

#define T_STEPS 256
#define BATCH 512

typedef _Float16 h2_t __attribute__((ext_vector_type(2)));

__device__ __forceinline__ float fdot2(uint32_t w, uint32_t c, float acc) {
#if __has_builtin(__builtin_amdgcn_fdot2)
    h2_t a, b;
    __builtin_memcpy(&a, &w, 4);
    __builtin_memcpy(&b, &c, 4);
    return __builtin_amdgcn_fdot2(a, b, acc, false);
#else
    union { uint32_t u; _Float16 h[2]; } A, B;
    A.u = w; B.u = c;
    return acc + (float)A.h[0]*(float)B.h[0] + (float)A.h[1]*(float)B.h[1];
#endif
}

__device__ __forceinline__ float sigmoidf_(float x) {
    return 1.f / (1.f + __expf(-x));
}
__device__ __forceinline__ float tanhf_(float x) {
    float ax = fabsf(x);
    float e = __expf(-2.f * ax);
    float r = (1.f - e) / (1.f + e);
    return copysignf(r, x);
}

// ---------------- prep: concat QCNN weights into one buffer ----------------
__global__ void concat_qw(const float* __restrict__ fm_w, const float* __restrict__ fm_b,
                          const float* __restrict__ c1_w, const float* __restrict__ c1_b,
                          const float* __restrict__ p1_w, const float* __restrict__ p1_b,
                          const float* __restrict__ c2_w, const float* __restrict__ c2_b,
                          const float* __restrict__ p2_w, const float* __restrict__ p2_b,
                          const float* __restrict__ c3_w, const float* __restrict__ c3_b,
                          float* __restrict__ qw) {
    for (int k = threadIdx.x; k < 780; k += 256) {
        float v;
        if      (k < 128) v = fm_w[k];
        else if (k < 144) v = fm_b[k-128];
        else if (k < 400) v = c1_w[k-144];
        else if (k < 416) v = c1_b[k-400];
        else if (k < 608) v = p1_w[k-416];
        else if (k < 620) v = p1_b[k-608];
        else if (k < 716) v = c2_w[k-620];
        else if (k < 724) v = c2_b[k-716];
        else if (k < 756) v = p2_w[k-724];
        else if (k < 760) v = p2_b[k-756];
        else if (k < 776) v = c3_w[k-760];
        else              v = c3_b[k-776];
        qw[k] = v;
    }
}

// ---------------- prep: pack LSTM gate weights to f16, K-reordered ----------------
// K layout per output o: k=0..255 -> h, k=256..259 -> x, k=260..263 -> zero pad.
// pair index p = 0..131 holds (2p, 2p+1). p<100 -> wregT[p][o]; p>=100 -> wtail[kq][o][c].
__global__ void pack_w(const float* __restrict__ f_w, const float* __restrict__ i_w,
                       const float* __restrict__ u_w, const float* __restrict__ o_w,
                       uint32_t* __restrict__ wregT, uint32_t* __restrict__ wtail) {
    int o = blockIdx.x;                       // 0..1023
    int p = blockIdx.y * 64 + threadIdx.x;    // 0..191
    if (p >= 132) return;
    int g = o >> 8, j = o & 255;
    const float* W = (g == 0) ? f_w : (g == 1) ? i_w : (g == 2) ? u_w : o_w;
    float v0 = 0.f, v1 = 0.f;
    int k0 = 2*p, k1 = 2*p + 1;
    if (k0 < 256) v0 = W[j*260 + 4 + k0]; else if (k0 < 260) v0 = W[j*260 + (k0-256)];
    if (k1 < 256) v1 = W[j*260 + 4 + k1]; else if (k1 < 260) v1 = W[j*260 + (k1-256)];
    union { uint32_t u; _Float16 h[2]; } P;
    P.h[0] = (_Float16)v0; P.h[1] = (_Float16)v1;
    if (p < 100) {
        wregT[p*1024 + o] = P.u;
    } else {
        int q = p - 100;                      // 0..31
        wtail[(((q >> 2) * 1024) + o) * 4 + (q & 3)] = P.u;
    }
}

// ---------------- QCNN feature extractor: one thread per (t,b) row ----------------
__global__ void qcnn_kernel(const float* __restrict__ in, const float* __restrict__ qw,
                            _Float16* __restrict__ feats) {
    int r = blockIdx.x * 256 + threadIdx.x;   // 0..131071
    const float* x = in + (size_t)r * 8;
    float v0[8];
#pragma unroll
    for (int i = 0; i < 8; ++i) v0[i] = x[i];
    float v1[16];
#pragma unroll
    for (int o = 0; o < 16; ++o) {
        float s = qw[128 + o];
#pragma unroll
        for (int i = 0; i < 8; ++i) s += qw[o*8 + i] * v0[i];
        v1[o] = tanhf_(s);
    }
    float v2[16];
#pragma unroll
    for (int o = 0; o < 16; ++o) {
        float s = qw[400 + o];
#pragma unroll
        for (int i = 0; i < 16; ++i) s += qw[144 + o*16 + i] * v1[i];
        v2[o] = tanhf_(s);
    }
    float v3[12];
#pragma unroll
    for (int o = 0; o < 12; ++o) {
        float s = qw[608 + o];
#pragma unroll
        for (int i = 0; i < 16; ++i) s += qw[416 + o*16 + i] * v2[i];
        v3[o] = tanhf_(s);
    }
    float v4[8];
#pragma unroll
    for (int o = 0; o < 8; ++o) {
        float s = qw[716 + o];
#pragma unroll
        for (int i = 0; i < 12; ++i) s += qw[620 + o*12 + i] * v3[i];
        v4[o] = tanhf_(s);
    }
    float v5[4];
#pragma unroll
    for (int o = 0; o < 4; ++o) {
        float s = qw[756 + o];
#pragma unroll
        for (int i = 0; i < 8; ++i) s += qw[724 + o*8 + i] * v4[i];
        v5[o] = tanhf_(s);
    }
    union { uint32_t u[2]; _Float16 h[4]; } P;
#pragma unroll
    for (int o = 0; o < 4; ++o) {
        float s = qw[776 + o];
#pragma unroll
        for (int i = 0; i < 4; ++i) s += qw[760 + o*4 + i] * v5[i];
        P.h[o] = (_Float16)tanhf_(s);
    }
    *reinterpret_cast<uint2*>(feats + (size_t)r * 4) = make_uint2(P.u[0], P.u[1]);
}

// ---------------- persistent LSTM: 256 blocks x 512 threads, 2 samples/block ----------------
#define DOT4(acc, warr, base, c4)                 \
    acc = fdot2(warr[(base)+0], (c4).x, acc);     \
    acc = fdot2(warr[(base)+1], (c4).y, acc);     \
    acc = fdot2(warr[(base)+2], (c4).z, acc);     \
    acc = fdot2(warr[(base)+3], (c4).w, acc);

#define DOTT(acc, tw, c4)                         \
    acc = fdot2((tw).x, (c4).x, acc);             \
    acc = fdot2((tw).y, (c4).y, acc);             \
    acc = fdot2((tw).z, (c4).z, acc);             \
    acc = fdot2((tw).w, (c4).w, acc);

__global__ __launch_bounds__(512, 2)
void lstm_kernel(const uint32_t* __restrict__ wregT, const uint4* __restrict__ wtailG,
                 const _Float16* __restrict__ feats,
                 const float* __restrict__ f_b, const float* __restrict__ i_b,
                 const float* __restrict__ u_b, const float* __restrict__ o_b,
                 const float* __restrict__ head_w, const float* __restrict__ head_bp,
                 float* __restrict__ out) {
    __shared__ uint4 tailL[8192];                        // 128 KB  (weights K=200..263)
    __shared__ __align__(16) uint32_t combU[2][132];     // [sample][pair] f16x2: h(0..255),x(256..259),pad
    __shared__ float gbuf[2][1024];                      // gate pre-activations
    __shared__ float hw[256];                            // head weights
    __shared__ float red[8];                             // head partial sums

    const int tid = threadIdx.x;
    const int o0 = tid, o1 = tid + 512;
    const int j  = tid & 255;
    const int g0 = tid >> 8;                 // 0 -> (f,u) owner, 1 -> (i,o) owner
    const int s0 = blockIdx.x * 2;

    // stationary register weights: K pairs 0..99 for two outputs
    uint32_t w0[100], w1[100];
#pragma unroll
    for (int p = 0; p < 100; ++p) w0[p] = wregT[p*1024 + o0];
#pragma unroll
    for (int p = 0; p < 100; ++p) w1[p] = wregT[p*1024 + o1];

    const float bias0 = (g0 == 0 ? f_b : i_b)[j];
    const float bias1 = (g0 == 0 ? u_b : o_b)[j];
    const float hb = head_bp[0];

    for (int idx = tid; idx < 8192; idx += 512) tailL[idx] = wtailG[idx];
    if (tid < 256) hw[tid] = head_w[tid];
    _Float16* combH = reinterpret_cast<_Float16*>(&combU[0][0]);
    for (int idx = tid; idx < 528; idx += 512) combH[idx] = (_Float16)0.f;
    __syncthreads();
    if (tid < 8) {   // x_0
        const int bb = tid >> 2, k = tid & 3;
        combH[bb*264 + 256 + k] = feats[((size_t)0*BATCH + (s0+bb))*4 + k];
    }
    __syncthreads();

    const uint4* cb0p = reinterpret_cast<const uint4*>(&combU[0][0]);
    const uint4* cb1p = reinterpret_cast<const uint4*>(&combU[1][0]);

    float creg = 0.f;
#pragma unroll 1
    for (int t = 0; t < T_STEPS; ++t) {
        // prefetch next x into registers (latency hides under dot phase)
        _Float16 xnext = (_Float16)0.f;
        const bool xload = (tid < 8) && (t + 1 < T_STEPS);
        if (xload) {
            const int bb = tid >> 2, k = tid & 3;
            xnext = feats[((size_t)(t+1)*BATCH + (s0+bb))*4 + k];
        }

        float a00 = bias0, a01 = bias0, a10 = bias1, a11 = bias1;
#pragma unroll
        for (int q = 0; q < 25; ++q) {
            const uint4 c0 = cb0p[q];
            const uint4 c1 = cb1p[q];
            DOT4(a00, w0, 4*q, c0)
            DOT4(a01, w0, 4*q, c1)
            DOT4(a10, w1, 4*q, c0)
            DOT4(a11, w1, 4*q, c1)
        }
#pragma unroll
        for (int q = 0; q < 8; ++q) {
            const uint4 tw0 = tailL[q*1024 + o0];
            const uint4 tw1 = tailL[q*1024 + o1];
            const uint4 c0 = cb0p[25 + q];
            const uint4 c1 = cb1p[25 + q];
            DOTT(a00, tw0, c0)
            DOTT(a01, tw0, c1)
            DOTT(a10, tw1, c0)
            DOTT(a11, tw1, c1)
        }
        gbuf[0][o0] = a00; gbuf[1][o0] = a01;
        gbuf[0][o1] = a10; gbuf[1][o1] = a11;
        __syncthreads();                                  // (A)

        const int b = g0;
        const float fg = sigmoidf_(gbuf[b][j]);
        const float ig = sigmoidf_(gbuf[b][256 + j]);
        const float ug = tanhf_(gbuf[b][512 + j]);
        const float og = sigmoidf_(gbuf[b][768 + j]);
        creg = fg * creg + ig * ug;
        const float h = og * tanhf_(creg);

        float p = h * hw[j];
#pragma unroll
        for (int off = 32; off > 0; off >>= 1) p += __shfl_down(p, off);
        if ((tid & 63) == 0) red[tid >> 6] = p;

        combH[b*264 + j] = (_Float16)h;
        if (xload) {
            const int bb = tid >> 2, k = tid & 3;
            combH[bb*264 + 256 + k] = xnext;
        }
        __syncthreads();                                  // (B)

        if (tid < 2) {
            out[(size_t)t*BATCH + s0 + tid] =
                red[tid*4+0] + red[tid*4+1] + red[tid*4+2] + red[tid*4+3] + hb;
        }
    }
}

extern "C" void kernel_launch(void* const* d_in, const int* in_sizes, int n_in,
                              void* d_out, int out_size, void* d_ws, size_t ws_size,
                              hipStream_t stream) {
    const float* inputs = (const float*)d_in[0];
    const float* fm_w = (const float*)d_in[1];  const float* fm_b = (const float*)d_in[2];
    const float* c1_w = (const float*)d_in[3];  const float* c1_b = (const float*)d_in[4];
    const float* p1_w = (const float*)d_in[5];  const float* p1_b = (const float*)d_in[6];
    const float* c2_w = (const float*)d_in[7];  const float* c2_b = (const float*)d_in[8];
    const float* p2_w = (const float*)d_in[9];  const float* p2_b = (const float*)d_in[10];
    const float* c3_w = (const float*)d_in[11]; const float* c3_b = (const float*)d_in[12];
    const float* f_w  = (const float*)d_in[13]; const float* f_b  = (const float*)d_in[14];
    const float* i_w  = (const float*)d_in[15]; const float* i_b  = (const float*)d_in[16];
    const float* u_w  = (const float*)d_in[17]; const float* u_b  = (const float*)d_in[18];
    const float* o_w  = (const float*)d_in[19]; const float* o_b  = (const float*)d_in[20];
    const float* head_w = (const float*)d_in[21];
    const float* head_b = (const float*)d_in[22];

    // workspace layout (all 16B aligned)
    uint32_t*  wregT = (uint32_t*)d_ws;                               // 409600 B
    uint32_t*  wtail = (uint32_t*)((char*)d_ws + 409600);             // 131072 B
    _Float16*  feats = (_Float16*)((char*)d_ws + 540672);             // 1048576 B
    float*     qw    = (float*)((char*)d_ws + 1589248);               // 3120 B

    hipLaunchKernelGGL(concat_qw, dim3(1), dim3(256), 0, stream,
                       fm_w, fm_b, c1_w, c1_b, p1_w, p1_b, c2_w, c2_b,
                       p2_w, p2_b, c3_w, c3_b, qw);
    hipLaunchKernelGGL(pack_w, dim3(1024, 3), dim3(64), 0, stream,
                       f_w, i_w, u_w, o_w, wregT, wtail);
    hipLaunchKernelGGL(qcnn_kernel, dim3(512), dim3(256), 0, stream,
                       inputs, qw, feats);
    hipLaunchKernelGGL(lstm_kernel, dim3(256), dim3(512), 0, stream,
                       wregT, (const uint4*)wtail, feats,
                       f_b, i_b, u_b, o_b, head_w, head_b, (float*)d_out);
}